// Round 1
// baseline (2682.450 us; speedup 1.0000x reference)
//
#include <hip/hip_runtime.h>

// Model: x[2048,64,2] -> MLP(2->16 relu ->16) -> 8x LSTM(H=64) -> MLP(64->32 relu ->4)
// B=2048, T=64, H=64. All fp32.
//
// LSTM layer kernel: grid 256 blocks x 256 threads, M=8 batch rows/block.
// Thread n holds gate-row n of W=[w_ih | w_hh] (K=I+64 floats) in registers.
// Per step: stage in=[x_t|h] in LDS [k][m]; GEMM via broadcast b128 reads;
// gates through LDS for c/h update (c in VGPRs). 2 barriers/step.

#define BATCH 2048
#define TT 64
#define HH 64

__device__ __forceinline__ float sigmoid_fast(float x) {
    x = fminf(15.f, fmaxf(-15.f, x));
    return __builtin_amdgcn_rcpf(1.f + __expf(-x));
}
__device__ __forceinline__ float tanh_fast(float x) {
    x = fminf(15.f, fmaxf(-15.f, x));
    const float e = __expf(-2.f * x);
    return (1.f - e) * __builtin_amdgcn_rcpf(1.f + e);
}

// ---------------- input MLP: 2 -> 16 relu -> 16 ----------------
__global__ __launch_bounds__(256)
void mlp_in_kernel(const float* __restrict__ x,
                   const float* __restrict__ w1, const float* __restrict__ b1,
                   const float* __restrict__ w2, const float* __restrict__ b2,
                   float* __restrict__ out) {
    const int gid = blockIdx.x * 256 + threadIdx.x;  // one (b,t) per thread
    const float x0 = x[gid * 2 + 0];
    const float x1 = x[gid * 2 + 1];
    float hid[16];
#pragma unroll
    for (int j = 0; j < 16; ++j) {
        float v = fmaf(x1, w1[j * 2 + 1], fmaf(x0, w1[j * 2 + 0], b1[j]));
        hid[j] = fmaxf(0.f, v);
    }
    float o[16];
#pragma unroll
    for (int oo = 0; oo < 16; ++oo) {
        float acc = b2[oo];
#pragma unroll
        for (int j = 0; j < 16; ++j) acc = fmaf(hid[j], w2[oo * 16 + j], acc);
        o[oo] = acc;
    }
    float4* op = (float4*)(out + gid * 16);
#pragma unroll
    for (int q = 0; q < 4; ++q) {
        float4 v;
        v.x = o[q * 4 + 0]; v.y = o[q * 4 + 1]; v.z = o[q * 4 + 2]; v.w = o[q * 4 + 3];
        op[q] = v;
    }
}

// ---------------- LSTM layer (K = I + 64, I in {16,64}) ----------------
template <int K>
__global__ __launch_bounds__(256, 1)
void lstm_layer_k(const float* __restrict__ xin,
                  const float* __restrict__ w_ih, const float* __restrict__ w_hh,
                  const float* __restrict__ b_ih, const float* __restrict__ b_hh,
                  float* __restrict__ hout) {
    constexpr int I = K - 64;
    constexpr int M = 8;
    __shared__ __align__(16) float in_s[K * M];   // [k][m]
    __shared__ float g_s[M * 256];                // [m][gate-row]

    const int n = threadIdx.x;       // gate row 0..255  (i:0-63 f:64-127 g:128-191 o:192-255)
    const int base = blockIdx.x * M; // batch rows

    // --- load this gate-row's weights into registers (reused all 64 steps) ---
    float wreg[K];
    {
        const float4* wi = (const float4*)(w_ih + n * I);
#pragma unroll
        for (int q = 0; q < I / 4; ++q) {
            float4 v = wi[q];
            wreg[q * 4 + 0] = v.x; wreg[q * 4 + 1] = v.y;
            wreg[q * 4 + 2] = v.z; wreg[q * 4 + 3] = v.w;
        }
        const float4* wh = (const float4*)(w_hh + n * 64);
#pragma unroll
        for (int q = 0; q < 16; ++q) {
            float4 v = wh[q];
            wreg[I + q * 4 + 0] = v.x; wreg[I + q * 4 + 1] = v.y;
            wreg[I + q * 4 + 2] = v.z; wreg[I + q * 4 + 3] = v.w;
        }
    }
    const float bsum = b_ih[n] + b_hh[n];

    // zero in_s (h part must start at 0)
    for (int e = n; e < K * M; e += 256) in_s[e] = 0.f;

    // cell state for the two (m,j) update slots this thread owns
    float c0 = 0.f, c1 = 0.f;
    const int uj = n & 63;
    const int um0 = n >> 6;       // 0..3
    const int um1 = um0 + 4;      // 4..7

    for (int t = 0; t < TT; ++t) {
        // ---- phase A: stage x_t into in_s[k<I][m] ----
        if constexpr (I == 16) {
            if (n < M * 16) {
                const int m = n >> 4, k = n & 15;
                in_s[k * M + m] = xin[((base + m) * TT + t) * 16 + k];
            }
        } else {
#pragma unroll
            for (int r = 0; r < 2; ++r) {
                const int e = n + r * 256;
                const int m = e >> 6, k = e & 63;
                in_s[k * M + m] = xin[((base + m) * TT + t) * 64 + k];
            }
        }
        __syncthreads();

        // ---- phase B: gates[n][m] = bsum + sum_k W[n][k]*in[k][m] ----
        float acc[M];
#pragma unroll
        for (int m = 0; m < M; ++m) acc[m] = bsum;
#pragma unroll
        for (int k = 0; k < K; ++k) {
            const float w = wreg[k];
            const float4 a0 = *(const float4*)&in_s[k * M + 0];
            const float4 a1 = *(const float4*)&in_s[k * M + 4];
            acc[0] = fmaf(w, a0.x, acc[0]);
            acc[1] = fmaf(w, a0.y, acc[1]);
            acc[2] = fmaf(w, a0.z, acc[2]);
            acc[3] = fmaf(w, a0.w, acc[3]);
            acc[4] = fmaf(w, a1.x, acc[4]);
            acc[5] = fmaf(w, a1.y, acc[5]);
            acc[6] = fmaf(w, a1.z, acc[6]);
            acc[7] = fmaf(w, a1.w, acc[7]);
        }
#pragma unroll
        for (int m = 0; m < M; ++m) g_s[m * 256 + n] = acc[m];
        __syncthreads();

        // ---- phase C: elementwise LSTM update for 2 (m,j) slots ----
        {
            const int m = um0;
            const float gi = g_s[m * 256 + 0 + uj];
            const float gf = g_s[m * 256 + 64 + uj];
            const float gg = g_s[m * 256 + 128 + uj];
            const float go = g_s[m * 256 + 192 + uj];
            const float iv = sigmoid_fast(gi), fv = sigmoid_fast(gf);
            const float gv = tanh_fast(gg), ov = sigmoid_fast(go);
            c0 = fv * c0 + iv * gv;
            const float h = ov * tanh_fast(c0);
            in_s[(I + uj) * M + m] = h;
            hout[((base + m) * TT + t) * HH + uj] = h;
        }
        {
            const int m = um1;
            const float gi = g_s[m * 256 + 0 + uj];
            const float gf = g_s[m * 256 + 64 + uj];
            const float gg = g_s[m * 256 + 128 + uj];
            const float go = g_s[m * 256 + 192 + uj];
            const float iv = sigmoid_fast(gi), fv = sigmoid_fast(gf);
            const float gv = tanh_fast(gg), ov = sigmoid_fast(go);
            c1 = fv * c1 + iv * gv;
            const float h = ov * tanh_fast(c1);
            in_s[(I + uj) * M + m] = h;
            hout[((base + m) * TT + t) * HH + uj] = h;
        }
        // no barrier needed here: next phase A writes only the x-region of in_s,
        // and the post-A barrier orders phase-C h-writes before phase B reads.
    }
}

// ---------------- output MLP: 64 -> 32 relu -> 4 ----------------
__global__ __launch_bounds__(256)
void mlp_out_kernel(const float* __restrict__ hin,
                    const float* __restrict__ wo1, const float* __restrict__ bo1,
                    const float* __restrict__ wo2, const float* __restrict__ bo2,
                    float* __restrict__ out) {
    __shared__ __align__(16) float wo1_s[32 * 64];
    __shared__ float bo1_s[32];
    __shared__ float wo2_s[4 * 32];
    __shared__ float bo2_s[4];
    const int tid = threadIdx.x;
    for (int e = tid; e < 32 * 64; e += 256) wo1_s[e] = wo1[e];
    if (tid < 32) bo1_s[tid] = bo1[tid];
    if (tid < 128) wo2_s[tid] = wo2[tid];
    if (tid < 4) bo2_s[tid] = bo2[tid];
    __syncthreads();

    const int gid = blockIdx.x * 256 + tid;  // one (b,t) per thread
    const float4* hv = (const float4*)(hin + gid * 64);
    float4 h[16];
#pragma unroll
    for (int q = 0; q < 16; ++q) h[q] = hv[q];

    float m1[32];
#pragma unroll
    for (int o = 0; o < 32; ++o) {
        float acc = bo1_s[o];
        const float4* wrow = (const float4*)(wo1_s + o * 64);
#pragma unroll
        for (int q = 0; q < 16; ++q) {
            const float4 w = wrow[q];
            acc = fmaf(h[q].x, w.x, acc);
            acc = fmaf(h[q].y, w.y, acc);
            acc = fmaf(h[q].z, w.z, acc);
            acc = fmaf(h[q].w, w.w, acc);
        }
        m1[o] = fmaxf(0.f, acc);
    }
    float4 res;
    float r[4];
#pragma unroll
    for (int q = 0; q < 4; ++q) {
        float acc = bo2_s[q];
#pragma unroll
        for (int o = 0; o < 32; ++o) acc = fmaf(m1[o], wo2_s[q * 32 + o], acc);
        r[q] = acc;
    }
    res.x = r[0]; res.y = r[1]; res.z = r[2]; res.w = r[3];
    ((float4*)out)[gid] = res;
}

extern "C" void kernel_launch(void* const* d_in, const int* in_sizes, int n_in,
                              void* d_out, int out_size, void* d_ws, size_t ws_size,
                              hipStream_t stream) {
    const float* x     = (const float*)d_in[0];
    const float* w1    = (const float*)d_in[1];
    const float* b1    = (const float*)d_in[2];
    const float* w2    = (const float*)d_in[3];
    const float* b2    = (const float*)d_in[4];
    const float* w_ih0 = (const float*)d_in[5];
    const float* w_hh0 = (const float*)d_in[6];
    const float* b_ih0 = (const float*)d_in[7];
    const float* b_hh0 = (const float*)d_in[8];
    const float* w_ih  = (const float*)d_in[9];
    const float* w_hh  = (const float*)d_in[10];
    const float* b_ih  = (const float*)d_in[11];
    const float* b_hh  = (const float*)d_in[12];
    const float* wo1   = (const float*)d_in[13];
    const float* bo1   = (const float*)d_in[14];
    const float* wo2   = (const float*)d_in[15];
    const float* bo2   = (const float*)d_in[16];

    // workspace layout (75.5 MB total):
    //   buf_mlp: B*T*16 fp32 (8.4 MB) | bufA: B*T*64 (33.6 MB) | bufB: B*T*64
    float* buf_mlp = (float*)d_ws;
    float* bufA = buf_mlp + (size_t)BATCH * TT * 16;
    float* bufB = bufA + (size_t)BATCH * TT * 64;

    const int nbt_blocks = (BATCH * TT) / 256;  // 512

    mlp_in_kernel<<<nbt_blocks, 256, 0, stream>>>(x, w1, b1, w2, b2, buf_mlp);

    lstm_layer_k<80><<<BATCH / 8, 256, 0, stream>>>(buf_mlp, w_ih0, w_hh0, b_ih0, b_hh0, bufA);

    const float* cur = bufA;
    float* nxt = bufB;
    for (int l = 0; l < 7; ++l) {
        lstm_layer_k<128><<<BATCH / 8, 256, 0, stream>>>(
            cur, w_ih + (size_t)l * 256 * 64, w_hh + (size_t)l * 256 * 64,
            b_ih + (size_t)l * 256, b_hh + (size_t)l * 256, nxt);
        const float* tmp = nxt;
        nxt = (float*)cur;
        cur = tmp;
    }

    mlp_out_kernel<<<nbt_blocks, 256, 0, stream>>>(cur, wo1, bo1, wo2, bo2, (float*)d_out);
}

// Round 2
// 770.864 us; speedup vs baseline: 3.4798x; 3.4798x over previous
//
#include <hip/hip_runtime.h>

// Model: x[2048,64,2] -> MLP(2->16 relu ->16) -> 8x LSTM(H=64) -> MLP(64->32 relu ->4)
// B=2048, T=64, H=64, fp32 in/out.
//
// LSTM layer via split-bf16 MFMA (hi+lo, 3-term products => ~fp32 accuracy):
//   grid 512 blocks x 256 threads, M=4 batch rows/block (2 blocks/CU).
//   Weights W=[w_ih|w_hh] pre-split into bf16 hi/lo B-fragments in registers.
//   Step input panel [x_t | h] kept in LDS as bf16 hi/lo planes (split by writers).
//   Phase B: 2x ds_read_b128 per k-tile -> 3 MFMA per (ktile,ntile) -> gates to LDS.
//   Phase C: elementwise c/h update in fp32 (c in VGPRs), h split back into panel.

#define BATCH 2048
#define TT 64
#define HH 64

typedef short bf16x8 __attribute__((ext_vector_type(8)));
typedef float f32x4 __attribute__((ext_vector_type(4)));

__device__ __forceinline__ float sigmoid_fast(float x) {
    x = fminf(15.f, fmaxf(-15.f, x));
    return __builtin_amdgcn_rcpf(1.f + __expf(-x));
}
__device__ __forceinline__ float tanh_fast(float x) {
    x = fminf(15.f, fmaxf(-15.f, x));
    const float e = __expf(-2.f * x);
    return (1.f - e) * __builtin_amdgcn_rcpf(1.f + e);
}

// split fp32 -> bf16 hi (truncate) + bf16 lo (truncate of exact residual).
// residual after both ~2^-16 relative; dropped lo*lo term is ~2^-16 as well.
__device__ __forceinline__ void split2(float x, unsigned short& hi, unsigned short& lo) {
    const unsigned u = __float_as_uint(x);
    hi = (unsigned short)(u >> 16);
    const float r = x - __uint_as_float(u & 0xFFFF0000u);  // exact
    lo = (unsigned short)(__float_as_uint(r) >> 16);
}

// ---------------- input MLP: 2 -> 16 relu -> 16 ----------------
__global__ __launch_bounds__(256)
void mlp_in_kernel(const float* __restrict__ x,
                   const float* __restrict__ w1, const float* __restrict__ b1,
                   const float* __restrict__ w2, const float* __restrict__ b2,
                   float* __restrict__ out) {
    const int gid = blockIdx.x * 256 + threadIdx.x;  // one (b,t) per thread
    const float x0 = x[gid * 2 + 0];
    const float x1 = x[gid * 2 + 1];
    float hid[16];
#pragma unroll
    for (int j = 0; j < 16; ++j) {
        float v = fmaf(x1, w1[j * 2 + 1], fmaf(x0, w1[j * 2 + 0], b1[j]));
        hid[j] = fmaxf(0.f, v);
    }
    float o[16];
#pragma unroll
    for (int oo = 0; oo < 16; ++oo) {
        float acc = b2[oo];
#pragma unroll
        for (int j = 0; j < 16; ++j) acc = fmaf(hid[j], w2[oo * 16 + j], acc);
        o[oo] = acc;
    }
    float4* op = (float4*)(out + gid * 16);
#pragma unroll
    for (int q = 0; q < 4; ++q) {
        float4 v;
        v.x = o[q * 4 + 0]; v.y = o[q * 4 + 1]; v.z = o[q * 4 + 2]; v.w = o[q * 4 + 3];
        op[q] = v;
    }
}

// ---------------- LSTM layer, split-bf16 MFMA ----------------
// I = real input width (16 or 64); IPAD = padded x-region (32 or 64); K = IPAD+64.
template <int I, int IPAD>
__global__ __launch_bounds__(256, 2)
void lstm_mfma(const float* __restrict__ xin,
               const float* __restrict__ w_ih, const float* __restrict__ w_hh,
               const float* __restrict__ b_ih, const float* __restrict__ b_hh,
               float* __restrict__ hout) {
    constexpr int K = IPAD + 64;
    constexpr int KT = K / 32;       // k-tiles of 32
    constexpr int LDPS = K + 8;      // panel stride (shorts): mult of 8 -> b128-aligned rows,
                                     // 16B-row-offset pattern gives only 2-way (free) conflicts
    __shared__ unsigned short ph[16 * LDPS];  // panel hi plane [row 0..15][k]
    __shared__ unsigned short pl[16 * LDPS];  // panel lo plane
    __shared__ float g_s[4 * 256];            // gates [m][n]

    const int tid = threadIdx.x;
    const int wave = tid >> 6;
    const int lane = tid & 63;
    const int l16 = lane & 15;
    const int quad = lane >> 4;
    const int base = blockIdx.x * 4;  // 4 batch rows per block

    // zero panels: rows 4..15 and x-pad stay zero forever (A rows 4..15 are padding)
    for (int e = tid; e < 16 * LDPS; e += 256) { ph[e] = 0; pl[e] = 0; }

    // --- build B fragments (weights, split hi/lo) in registers ---
    // B[k][n] = W[n][k]; lane holds k = kt*32 + quad*8 + j, n = wave*64 + nt*16 + l16
    bf16x8 bhi[KT][4], blo[KT][4];
    float bias[4];
#pragma unroll
    for (int nt = 0; nt < 4; ++nt) {
        const int n = wave * 64 + nt * 16 + l16;
        bias[nt] = b_ih[n] + b_hh[n];
#pragma unroll
        for (int kt = 0; kt < KT; ++kt) {
#pragma unroll
            for (int j = 0; j < 8; ++j) {
                const int k = kt * 32 + quad * 8 + j;
                float w = 0.f;
                if (k < I) w = w_ih[n * I + k];
                else if (k >= IPAD) w = w_hh[n * 64 + (k - IPAD)];
                unsigned short h_, l_;
                split2(w, h_, l_);
                bhi[kt][nt][j] = (short)h_;
                blo[kt][nt][j] = (short)l_;
            }
        }
    }

    float c = 0.f;              // cell state: thread owns slot (m=wave, j=lane)
    const int cm = wave;
    const int cj = lane;

    for (int t = 0; t < TT; ++t) {
        // ---- phase A: stage x_t into panel (split bf16) ----
        if (I == 64) {
            const int m = tid >> 6, k = tid & 63;
            unsigned short h_, l_;
            split2(xin[((size_t)(base + m) * TT + t) * 64 + k], h_, l_);
            ph[m * LDPS + k] = h_;
            pl[m * LDPS + k] = l_;
        } else {
            if (tid < 64) {
                const int m = tid >> 4, k = tid & 15;
                unsigned short h_, l_;
                split2(xin[((size_t)(base + m) * TT + t) * 16 + k], h_, l_);
                ph[m * LDPS + k] = h_;
                pl[m * LDPS + k] = l_;
            }
        }
        __syncthreads();

        // ---- phase B: gates = bias + in @ W^T via 3-term split-bf16 MFMA ----
        f32x4 acc[4];
#pragma unroll
        for (int nt = 0; nt < 4; ++nt) {
            acc[nt][0] = bias[nt]; acc[nt][1] = bias[nt];
            acc[nt][2] = bias[nt]; acc[nt][3] = bias[nt];
        }
#pragma unroll
        for (int kt = 0; kt < KT; ++kt) {
            const int aoff = l16 * LDPS + kt * 32 + quad * 8;
            const bf16x8 ahi = *(const bf16x8*)&ph[aoff];
            const bf16x8 alo = *(const bf16x8*)&pl[aoff];
#pragma unroll
            for (int nt = 0; nt < 4; ++nt) {
                acc[nt] = __builtin_amdgcn_mfma_f32_16x16x32_bf16(ahi, bhi[kt][nt], acc[nt], 0, 0, 0);
                acc[nt] = __builtin_amdgcn_mfma_f32_16x16x32_bf16(alo, bhi[kt][nt], acc[nt], 0, 0, 0);
                acc[nt] = __builtin_amdgcn_mfma_f32_16x16x32_bf16(ahi, blo[kt][nt], acc[nt], 0, 0, 0);
            }
        }
        // D layout: row = quad*4 + r, col = l16 (+16*nt +64*wave). Rows 0..3 (quad 0) are real.
        if (quad == 0) {
#pragma unroll
            for (int nt = 0; nt < 4; ++nt) {
                const int col = wave * 64 + nt * 16 + l16;
#pragma unroll
                for (int r = 0; r < 4; ++r) g_s[r * 256 + col] = acc[nt][r];
            }
        }
        __syncthreads();

        // ---- phase C: elementwise LSTM update, one (m,j) slot per thread ----
        {
            const float gi = g_s[cm * 256 + 0 + cj];
            const float gf = g_s[cm * 256 + 64 + cj];
            const float gg = g_s[cm * 256 + 128 + cj];
            const float go = g_s[cm * 256 + 192 + cj];
            const float iv = sigmoid_fast(gi), fv = sigmoid_fast(gf);
            const float gv = tanh_fast(gg), ov = sigmoid_fast(go);
            c = fv * c + iv * gv;
            const float h = ov * tanh_fast(c);
            unsigned short h_, l_;
            split2(h, h_, l_);
            ph[cm * LDPS + IPAD + cj] = h_;
            pl[cm * LDPS + IPAD + cj] = l_;
            hout[((size_t)(base + cm) * TT + t) * HH + cj] = h;
        }
        // no barrier here: next phase A writes only the x-region (disjoint from C's
        // h-writes/g_s reads); the post-A barrier orders everything for phase B.
    }
}

// ---------------- output MLP: 64 -> 32 relu -> 4 ----------------
__global__ __launch_bounds__(256)
void mlp_out_kernel(const float* __restrict__ hin,
                    const float* __restrict__ wo1, const float* __restrict__ bo1,
                    const float* __restrict__ wo2, const float* __restrict__ bo2,
                    float* __restrict__ out) {
    __shared__ __align__(16) float wo1_s[32 * 64];
    __shared__ float bo1_s[32];
    __shared__ float wo2_s[4 * 32];
    __shared__ float bo2_s[4];
    const int tid = threadIdx.x;
    for (int e = tid; e < 32 * 64; e += 256) wo1_s[e] = wo1[e];
    if (tid < 32) bo1_s[tid] = bo1[tid];
    if (tid < 128) wo2_s[tid] = wo2[tid];
    if (tid < 4) bo2_s[tid] = bo2[tid];
    __syncthreads();

    const int gid = blockIdx.x * 256 + tid;  // one (b,t) per thread
    const float4* hv = (const float4*)(hin + gid * 64);
    float4 h[16];
#pragma unroll
    for (int q = 0; q < 16; ++q) h[q] = hv[q];

    float m1[32];
#pragma unroll
    for (int o = 0; o < 32; ++o) {
        float acc = bo1_s[o];
        const float4* wrow = (const float4*)(wo1_s + o * 64);
#pragma unroll
        for (int q = 0; q < 16; ++q) {
            const float4 w = wrow[q];
            acc = fmaf(h[q].x, w.x, acc);
            acc = fmaf(h[q].y, w.y, acc);
            acc = fmaf(h[q].z, w.z, acc);
            acc = fmaf(h[q].w, w.w, acc);
        }
        m1[o] = fmaxf(0.f, acc);
    }
    float r[4];
#pragma unroll
    for (int q = 0; q < 4; ++q) {
        float acc = bo2_s[q];
#pragma unroll
        for (int o = 0; o < 32; ++o) acc = fmaf(m1[o], wo2_s[q * 32 + o], acc);
        r[q] = acc;
    }
    float4 res;
    res.x = r[0]; res.y = r[1]; res.z = r[2]; res.w = r[3];
    ((float4*)out)[gid] = res;
}

extern "C" void kernel_launch(void* const* d_in, const int* in_sizes, int n_in,
                              void* d_out, int out_size, void* d_ws, size_t ws_size,
                              hipStream_t stream) {
    const float* x     = (const float*)d_in[0];
    const float* w1    = (const float*)d_in[1];
    const float* b1    = (const float*)d_in[2];
    const float* w2    = (const float*)d_in[3];
    const float* b2    = (const float*)d_in[4];
    const float* w_ih0 = (const float*)d_in[5];
    const float* w_hh0 = (const float*)d_in[6];
    const float* b_ih0 = (const float*)d_in[7];
    const float* b_hh0 = (const float*)d_in[8];
    const float* w_ih  = (const float*)d_in[9];
    const float* w_hh  = (const float*)d_in[10];
    const float* b_ih  = (const float*)d_in[11];
    const float* b_hh  = (const float*)d_in[12];
    const float* wo1   = (const float*)d_in[13];
    const float* bo1   = (const float*)d_in[14];
    const float* wo2   = (const float*)d_in[15];
    const float* bo2   = (const float*)d_in[16];

    // workspace: buf_mlp B*T*16 | bufA B*T*64 | bufB B*T*64  (fp32)
    float* buf_mlp = (float*)d_ws;
    float* bufA = buf_mlp + (size_t)BATCH * TT * 16;
    float* bufB = bufA + (size_t)BATCH * TT * 64;

    const int nbt_blocks = (BATCH * TT) / 256;  // 512

    mlp_in_kernel<<<nbt_blocks, 256, 0, stream>>>(x, w1, b1, w2, b2, buf_mlp);

    lstm_mfma<16, 32><<<BATCH / 4, 256, 0, stream>>>(buf_mlp, w_ih0, w_hh0, b_ih0, b_hh0, bufA);

    const float* cur = bufA;
    float* nxt = bufB;
    for (int l = 0; l < 7; ++l) {
        lstm_mfma<64, 64><<<BATCH / 4, 256, 0, stream>>>(
            cur, w_ih + (size_t)l * 256 * 64, w_hh + (size_t)l * 256 * 64,
            b_ih + (size_t)l * 256, b_hh + (size_t)l * 256, nxt);
        const float* tmp = nxt;
        nxt = (float*)cur;
        cur = tmp;
    }

    mlp_out_kernel<<<nbt_blocks, 256, 0, stream>>>(cur, wo1, bo1, wo2, bo2, (float*)d_out);
}